// Round 6
// baseline (295.032 us; speedup 1.0000x reference)
//
#include <hip/hip_runtime.h>

typedef unsigned short u16;
typedef unsigned int u32;

typedef __bf16 bf16x8 __attribute__((ext_vector_type(8)));
typedef float f32x4 __attribute__((ext_vector_type(4)));

union FragI { int4 i; bf16x8 b; u16 u[8]; };

__device__ __forceinline__ u16 f2bf(float x) {
  u32 u = __float_as_uint(x);
  u32 r = (u + 0x7fffu + ((u >> 16) & 1u)) >> 16;
  return (u16)r;
}
__device__ __forceinline__ float bf2f(u16 h) {
  return __uint_as_float((u32)h << 16);
}
__device__ __forceinline__ float tanh_fast(float x) {
  float e = __expf(2.0f * x);
  return 1.0f - __fdividef(2.0f, e + 1.0f);
}
__device__ __forceinline__ bf16x8 load_cvt8(const float* __restrict__ p) {
  float4 f0 = *(const float4*)p;
  float4 f1 = *(const float4*)(p + 4);
  union { bf16x8 b; u16 u[8]; } t;
  t.u[0] = f2bf(f0.x); t.u[1] = f2bf(f0.y); t.u[2] = f2bf(f0.z); t.u[3] = f2bf(f0.w);
  t.u[4] = f2bf(f1.x); t.u[5] = f2bf(f1.y); t.u[6] = f2bf(f1.z); t.u[7] = f2bf(f1.w);
  return t.b;
}

#define GLDS(gptr, lptr) \
  __builtin_amdgcn_global_load_lds((const __attribute__((address_space(1))) u32*)(gptr), \
                                   (__attribute__((address_space(3))) u32*)(lptr), 16, 0, 0)

// ---------------- f32 -> bf16 conversion (W_out) ----------------
__global__ __launch_bounds__(256) void conv_v4(const float* __restrict__ in,
                                               u16* __restrict__ out, int n4) {
  int i = blockIdx.x * 256 + threadIdx.x;
  if (i >= n4) return;
  float4 f = ((const float4*)in)[i];
  union { u16 u[4]; int2 v; } o;
  o.u[0] = f2bf(f.x); o.u[1] = f2bf(f.y); o.u[2] = f2bf(f.z); o.u[3] = f2bf(f.w);
  ((int2*)out)[i] = o.v;
}

// ---------------- projection GEMM (bf16 output) ----------------
__global__ __launch_bounds__(256) void proj_gemm_bf(const float* __restrict__ A,
                                                    const float* __restrict__ Bw,
                                                    const float* __restrict__ bias,
                                                    u16* __restrict__ C,
                                                    int M, int N, int K) {
  int tid = threadIdx.x;
  int lane = tid & 63, wid = tid >> 6;
  int m0 = blockIdx.x * 64, n0 = blockIdx.y * 64;
  int kper = K >> 2;
  int kbase = wid * kper;
  int ksteps = kper >> 5;
  int r16 = lane & 15, khi = (lane >> 4) * 8;

  f32x4 z = {0.f, 0.f, 0.f, 0.f};
  f32x4 acc[4][4];
  for (int i = 0; i < 4; ++i)
    for (int j = 0; j < 4; ++j) acc[i][j] = z;

  for (int ks = 0; ks < ksteps; ++ks) {
    int k = kbase + ks * 32 + khi;
    bf16x8 af[4], bf[4];
#pragma unroll
    for (int fm = 0; fm < 4; ++fm)
      af[fm] = load_cvt8(A + (size_t)(m0 + fm * 16 + r16) * K + k);
#pragma unroll
    for (int fn = 0; fn < 4; ++fn)
      bf[fn] = load_cvt8(Bw + (size_t)(n0 + fn * 16 + r16) * K + k);
#pragma unroll
    for (int fm = 0; fm < 4; ++fm)
#pragma unroll
      for (int fn = 0; fn < 4; ++fn)
        acc[fm][fn] = __builtin_amdgcn_mfma_f32_16x16x32_bf16(af[fm], bf[fn], acc[fm][fn], 0, 0, 0);
  }

  __shared__ float red[4][64][64];
#pragma unroll
  for (int fm = 0; fm < 4; ++fm)
#pragma unroll
    for (int fn = 0; fn < 4; ++fn)
#pragma unroll
      for (int i = 0; i < 4; ++i)
        red[wid][fm * 16 + (lane >> 4) * 4 + i][fn * 16 + r16] = acc[fm][fn][i];
  __syncthreads();
  for (int idx = tid; idx < 4096; idx += 256) {
    int r = idx >> 6, c = idx & 63;
    float s = red[0][r][c] + red[1][r][c] + red[2][r][c] + red[3][r][c] + bias[n0 + c];
    C[(size_t)(m0 + r) * N + n0 + c] = f2bf(s);
  }
}

// ---------------- fused main GEMM ----------------
// A-tiles computed IN-KERNEL: A[r][k] = tanh(enc[bt0 + r/64][k] + pred[b*64 + r%64][k]),
// produced from bf16 enc/pred (2 MB, L2-hot) into swizzled LDS via ds_write (VALU pipe
// overlaps MFMA pipe across waves). B (Wo) staged via global_load_lds. One barrier per
// K-tile; the tanh's implicit VMEM drain proves B(t+1) landed (counted-by-construction).
// out: logits f32 [65536][1024] at 0, durations f32 [65536][5] at 67108864
#define LOGITS_N 67108864
#define WS_LD 648

// Stage full 256x64 bf16 B-tile (32 KB): 4 x GLDS(16B) per thread (512 thr).
// LDS phys (row, chunk) holds logical (row, chunk ^ (row&7))  [T2 swizzle, 8-u16 chunks]
__device__ __forceinline__ void stage_b(const u16* __restrict__ g, u16* l,
                                        int wid, int lane) {
  int rl = wid * 8 + (lane >> 3);
  int cl = ((lane & 7) ^ (lane >> 3)) * 8;
  const u16* gp = g + (size_t)rl * 640 + cl;
  u16* lp = l + wid * 512;
#pragma unroll
  for (int j = 0; j < 4; ++j)
    GLDS(gp + (size_t)j * 64 * 640, lp + j * 4096);
}

__global__ __launch_bounds__(512, 2) void main_fused(const u16* __restrict__ encB,
                                                     const u16* __restrict__ predB,
                                                     const u16* __restrict__ WoB,
                                                     const float* __restrict__ W_dur,
                                                     const float* __restrict__ b_out,
                                                     const float* __restrict__ b_dur,
                                                     float* __restrict__ out) {
  __shared__ __align__(16) u16 As[2][16384];  // 2 x 32 KB (256 rows x 64 k)
  __shared__ __align__(16) u16 Bs[2][16384];  // 2 x 32 KB
  __shared__ __align__(16) u16 Ws[16 * WS_LD];

  int tid = threadIdx.x;
  int lane = tid & 63, wid = tid >> 6;
  int bid = blockIdx.x;
  int swz = (bid & 7) * 128 + (bid >> 3);   // bijective XCD swizzle (1024 % 8 == 0)
  int bn = swz & 3, bm = swz >> 2;
  int m0 = bm * 256, n0 = bn * 256;
  int wr = wid >> 2, wc = wid & 3;          // per-wave C = 128 x 64
  int r16 = lane & 15, khi8 = (lane >> 4) * 8;
  int xorv = (r16 & 7) << 3;
  bool dur_blk = (bn == 0);
  bool do_dur = dur_blk && (wc == 0);

  // A-produce mapping: thread owns u-row ur, k-chunk kc; rows j*64+ur for j=0..3
  int ur = tid >> 3, kc = tid & 7;
  int bt0 = bm * 4;
  int pb = (bt0 >> 8) * 64;                 // batch row base in predB
  const u16* prp = predB + (size_t)(pb + ur) * 640 + kc * 8;
  const u16* enp = encB + (size_t)bt0 * 640 + kc * 8;
  int aw_off = ur * 64 + ((kc ^ (ur & 7)) << 3);  // +j*4096 per j (row j*64+ur)

  if (dur_blk) {
    for (int i = tid; i < 16 * WS_LD; i += 512) {
      int r = i / WS_LD, c = i - r * WS_LD;
      Ws[i] = (r < 5 && c < 640) ? f2bf(W_dur[r * 640 + c]) : (u16)0;
    }
  }

  const u16* WB = WoB + (size_t)n0 * 640;

  // prologue: stage B(0); produce A(0)
  stage_b(WB, Bs[0], wid, lane);
  {
    int4 pr = *(const int4*)(prp);
#pragma unroll
    for (int j = 0; j < 4; ++j) {
      int4 ev = *(const int4*)(enp + (size_t)j * 640);
      FragI e, q, h;
      e.i = ev; q.i = pr;
#pragma unroll
      for (int x = 0; x < 8; ++x)
        h.u[x] = f2bf(tanh_fast(bf2f(e.u[x]) + bf2f(q.u[x])));
      *(int4*)(As[0] + j * 4096 + aw_off) = h.i;
    }
  }
  asm volatile("s_waitcnt lgkmcnt(0)" ::: "memory");

  f32x4 z = {0.f, 0.f, 0.f, 0.f};
  f32x4 acc[8][4];
#pragma unroll
  for (int i = 0; i < 8; ++i)
#pragma unroll
    for (int j = 0; j < 4; ++j) acc[i][j] = z;
  f32x4 dacc[8];
#pragma unroll
  for (int i = 0; i < 8; ++i) dacc[i] = z;

#pragma unroll 2
  for (int t = 0; t < 10; ++t) {
    const int p = t & 1;
    __builtin_amdgcn_s_barrier();           // buffers p ready; 1-p free
    __builtin_amdgcn_sched_barrier(0);

    // issue next tile's inputs early (latency hidden under MFMA phase)
    int4 pr; int4 er[4];
    if (t < 9) {
      stage_b(WB + (t + 1) * 64, Bs[1 - p], wid, lane);
      pr = *(const int4*)(prp + (t + 1) * 64);
#pragma unroll
      for (int j = 0; j < 4; ++j)
        er[j] = *(const int4*)(enp + (size_t)j * 640 + (t + 1) * 64);
    }
    __builtin_amdgcn_sched_barrier(0);

    // ---- MFMA phase on tile t ----
    const u16* Ab = As[p];
    const u16* Bb = Bs[p];
    FragI bfr[4][2], wd[2];
#pragma unroll
    for (int fn = 0; fn < 4; ++fn)
#pragma unroll
      for (int ks = 0; ks < 2; ++ks)
        bfr[fn][ks].i = *(const int4*)(Bb + (wc * 64 + fn * 16 + r16) * 64 +
                                       ((ks * 32 + khi8) ^ xorv));
    if (do_dur) {
#pragma unroll
      for (int ks = 0; ks < 2; ++ks)
        wd[ks].i = *(const int4*)(Ws + r16 * WS_LD + t * 64 + ks * 32 + khi8);
    }
#pragma unroll
    for (int q = 0; q < 4; ++q) {
      FragI aq[2][2];
#pragma unroll
      for (int m = 0; m < 2; ++m)
#pragma unroll
        for (int ks = 0; ks < 2; ++ks)
          aq[m][ks].i = *(const int4*)(Ab + (wr * 128 + q * 32 + m * 16 + r16) * 64 +
                                       ((ks * 32 + khi8) ^ xorv));
      __builtin_amdgcn_s_setprio(1);
#pragma unroll
      for (int m = 0; m < 2; ++m)
#pragma unroll
        for (int ks = 0; ks < 2; ++ks) {
#pragma unroll
          for (int fn = 0; fn < 4; ++fn)
            acc[q * 2 + m][fn] = __builtin_amdgcn_mfma_f32_16x16x32_bf16(
                aq[m][ks].b, bfr[fn][ks].b, acc[q * 2 + m][fn], 0, 0, 0);
          if (do_dur)
            dacc[q * 2 + m] = __builtin_amdgcn_mfma_f32_16x16x32_bf16(
                aq[m][ks].b, wd[ks].b, dacc[q * 2 + m], 0, 0, 0);
        }
      __builtin_amdgcn_s_setprio(0);
    }
    __builtin_amdgcn_sched_barrier(0);

    // ---- produce A(t+1) into As[1-p] (tanh on VALU pipe) ----
    if (t < 9) {
      u16* Ad = As[1 - p];
#pragma unroll
      for (int j = 0; j < 4; ++j) {
        FragI e, q2, h;
        e.i = er[j]; q2.i = pr;
#pragma unroll
        for (int x = 0; x < 8; ++x)
          h.u[x] = f2bf(tanh_fast(bf2f(e.u[x]) + bf2f(q2.u[x])));
        *(int4*)(Ad + j * 4096 + aw_off) = h.i;
      }
    }
    asm volatile("s_waitcnt lgkmcnt(0)" ::: "memory");  // ds_reads + A-writes drained
    __builtin_amdgcn_sched_barrier(0);
  }

  // ---- epilogue ----
  int rb = m0 + wr * 128 + (lane >> 4) * 4;
  int cb = n0 + wc * 64 + r16;
#pragma unroll
  for (int fn = 0; fn < 4; ++fn) {
    int col = cb + fn * 16;
    float bo = b_out[col];
#pragma unroll
    for (int fm = 0; fm < 8; ++fm) {
      int row = rb + fm * 16;
#pragma unroll
      for (int i = 0; i < 4; ++i)
        out[(size_t)(row + i) * 1024 + col] = acc[fm][fn][i] + bo;
    }
  }
  if (do_dur && r16 < 5) {
    float bd = b_dur[r16];
#pragma unroll
    for (int fm = 0; fm < 8; ++fm) {
      int row = rb + fm * 16;
#pragma unroll
      for (int i = 0; i < 4; ++i)
        out[LOGITS_N + (size_t)(row + i) * 5 + r16] = dacc[fm][i] + bd;
    }
  }
}

extern "C" void kernel_launch(void* const* d_in, const int* in_sizes, int n_in,
                              void* d_out, int out_size, void* d_ws, size_t ws_size,
                              hipStream_t stream) {
  const float* encoder   = (const float*)d_in[0];
  const float* predictor = (const float*)d_in[1];
  const float* W_enc = (const float*)d_in[2];
  const float* b_enc = (const float*)d_in[3];
  const float* W_pred = (const float*)d_in[4];
  const float* b_pred = (const float*)d_in[5];
  const float* W_out = (const float*)d_in[6];
  const float* b_out = (const float*)d_in[7];
  const float* W_dur = (const float*)d_in[8];
  const float* b_dur = (const float*)d_in[9];
  float* out = (float*)d_out;

  char* ws = (char*)d_ws;
  u16* WoB   = (u16*)(ws);                // 1024*640*2 = 1,310,720 B
  u16* encB  = (u16*)(ws + 1310720);      // 1024*640*2 = 1,310,720 B
  u16* predB = (u16*)(ws + 2621440);      // 256*640*2  =   327,680 B

  conv_v4<<<640, 256, 0, stream>>>(W_out, WoB, 163840);
  proj_gemm_bf<<<dim3(16, 10), 256, 0, stream>>>(encoder, W_enc, b_enc, encB, 1024, 640, 1024);
  proj_gemm_bf<<<dim3(4, 10), 256, 0, stream>>>(predictor, W_pred, b_pred, predB, 256, 640, 640);
  main_fused<<<1024, 512, 0, stream>>>(encB, predB, WoB, W_dur, b_out, b_dur, out);
}

// Round 7
// 253.574 us; speedup vs baseline: 1.1635x; 1.1635x over previous
//
#include <hip/hip_runtime.h>

typedef unsigned short u16;
typedef unsigned int u32;

typedef __bf16 bf16x8 __attribute__((ext_vector_type(8)));
typedef float f32x4 __attribute__((ext_vector_type(4)));

union FragI { int4 i; bf16x8 b; u16 u[8]; };

__device__ __forceinline__ u16 f2bf(float x) {
  u32 u = __float_as_uint(x);
  u32 r = (u + 0x7fffu + ((u >> 16) & 1u)) >> 16;
  return (u16)r;
}
__device__ __forceinline__ float tanh_fast(float x) {
  float e = __expf(2.0f * x);
  return 1.0f - __fdividef(2.0f, e + 1.0f);
}
__device__ __forceinline__ bf16x8 load_cvt8(const float* __restrict__ p) {
  float4 f0 = *(const float4*)p;
  float4 f1 = *(const float4*)(p + 4);
  union { bf16x8 b; u16 u[8]; } t;
  t.u[0] = f2bf(f0.x); t.u[1] = f2bf(f0.y); t.u[2] = f2bf(f0.z); t.u[3] = f2bf(f0.w);
  t.u[4] = f2bf(f1.x); t.u[5] = f2bf(f1.y); t.u[6] = f2bf(f1.z); t.u[7] = f2bf(f1.w);
  return t.b;
}

// ---------------- f32 -> bf16 conversion (W_out) ----------------
__global__ __launch_bounds__(256) void conv_v4(const float* __restrict__ in,
                                               u16* __restrict__ out, int n4) {
  int i = blockIdx.x * 256 + threadIdx.x;
  if (i >= n4) return;
  float4 f = ((const float4*)in)[i];
  union { u16 u[4]; int2 v; } o;
  o.u[0] = f2bf(f.x); o.u[1] = f2bf(f.y); o.u[2] = f2bf(f.z); o.u[3] = f2bf(f.w);
  ((int2*)out)[i] = o.v;
}

// W_dur [5][640] f32 -> padded bf16 [16][640] (rows 5..15 zero)
__global__ __launch_bounds__(256) void conv_wdur(const float* __restrict__ in,
                                                 u16* __restrict__ out) {
  int i = blockIdx.x * 256 + threadIdx.x;
  if (i < 16 * 640) out[i] = (i < 5 * 640) ? f2bf(in[i]) : (u16)0;
}

// ---------------- projection GEMM (f32 out; verified R1-R5) ----------------
__global__ __launch_bounds__(256) void proj_gemm(const float* __restrict__ A,
                                                 const float* __restrict__ Bw,
                                                 const float* __restrict__ bias,
                                                 float* __restrict__ C,
                                                 int M, int N, int K) {
  int tid = threadIdx.x;
  int lane = tid & 63, wid = tid >> 6;
  int m0 = blockIdx.x * 64, n0 = blockIdx.y * 64;
  int kper = K >> 2;
  int kbase = wid * kper;
  int ksteps = kper >> 5;
  int r16 = lane & 15, khi = (lane >> 4) * 8;

  f32x4 z = {0.f, 0.f, 0.f, 0.f};
  f32x4 acc[4][4];
  for (int i = 0; i < 4; ++i)
    for (int j = 0; j < 4; ++j) acc[i][j] = z;

  for (int ks = 0; ks < ksteps; ++ks) {
    int k = kbase + ks * 32 + khi;
    bf16x8 af[4], bf[4];
#pragma unroll
    for (int fm = 0; fm < 4; ++fm)
      af[fm] = load_cvt8(A + (size_t)(m0 + fm * 16 + r16) * K + k);
#pragma unroll
    for (int fn = 0; fn < 4; ++fn)
      bf[fn] = load_cvt8(Bw + (size_t)(n0 + fn * 16 + r16) * K + k);
#pragma unroll
    for (int fm = 0; fm < 4; ++fm)
#pragma unroll
      for (int fn = 0; fn < 4; ++fn)
        acc[fm][fn] = __builtin_amdgcn_mfma_f32_16x16x32_bf16(af[fm], bf[fn], acc[fm][fn], 0, 0, 0);
  }

  __shared__ float red[4][64][64];
#pragma unroll
  for (int fm = 0; fm < 4; ++fm)
#pragma unroll
    for (int fn = 0; fn < 4; ++fn)
#pragma unroll
      for (int i = 0; i < 4; ++i)
        red[wid][fm * 16 + (lane >> 4) * 4 + i][fn * 16 + r16] = acc[fm][fn][i];
  __syncthreads();
  for (int idx = tid; idx < 4096; idx += 256) {
    int r = idx >> 6, c = idx & 63;
    float s = red[0][r][c] + red[1][r][c] + red[2][r][c] + red[3][r][c] + bias[n0 + c];
    C[(size_t)(m0 + r) * N + n0 + c] = s;
  }
}

// ---------------- bt-fused main: one block per bt; A-panel resident in LDS ----------------
// Block = bt (64 u-rows x full K=640). Prologue builds A = tanh(enc[bt]+pred[b,:]) in LDS
// (tanh computed ONCE). K-loop: NO barriers, NO staging — A-frags from LDS, B-frags direct
// from L2-hot Wo (1.3 MB shared by all 1024 blocks). Wave w owns cols w*64..w*64+63.
// Durations: wave 0 side-pass off the same LDS panel before the main loop.
// out: logits f32 [65536][1024] at 0, durations f32 [65536][5] at 67108864
#define LOGITS_N 67108864

__global__ __launch_bounds__(1024, 4) void bt_fused(const float* __restrict__ encP,
                                                    const float* __restrict__ predP,
                                                    const u16* __restrict__ WoB,
                                                    const u16* __restrict__ WdB,
                                                    const float* __restrict__ b_out,
                                                    const float* __restrict__ b_dur,
                                                    float* __restrict__ out) {
  __shared__ __align__(16) u16 As[64 * 640];  // 80 KiB, swizzled chunks

  int tid = threadIdx.x;
  int lane = tid & 63, wid = tid >> 6;
  int r16 = lane & 15, g4 = lane >> 4;
  int khi8 = g4 * 8;
  int bt = blockIdx.x;
  int pb = (bt >> 8) * 64;  // batch base row in predP

  // ---- prologue: build A-panel (64 rows x 640) with tanh, swizzled ds_write ----
  const float* encRow = encP + (size_t)bt * 640;
#pragma unroll
  for (int j = 0; j < 5; ++j) {
    int idx = j * 1024 + tid;          // 0..5119 chunk index
    int row = idx / 80;
    int c = idx - row * 80;            // k-chunk (8 elems)
    const float* ep = encRow + c * 8;
    const float* pp = predP + (size_t)(pb + row) * 640 + c * 8;
    float4 e0 = *(const float4*)ep;
    float4 e1 = *(const float4*)(ep + 4);
    float4 p0 = *(const float4*)pp;
    float4 p1 = *(const float4*)(pp + 4);
    FragI h;
    h.u[0] = f2bf(tanh_fast(e0.x + p0.x));
    h.u[1] = f2bf(tanh_fast(e0.y + p0.y));
    h.u[2] = f2bf(tanh_fast(e0.z + p0.z));
    h.u[3] = f2bf(tanh_fast(e0.w + p0.w));
    h.u[4] = f2bf(tanh_fast(e1.x + p1.x));
    h.u[5] = f2bf(tanh_fast(e1.y + p1.y));
    h.u[6] = f2bf(tanh_fast(e1.z + p1.z));
    h.u[7] = f2bf(tanh_fast(e1.w + p1.w));
    *(int4*)(As + row * 640 + ((c ^ (row & 7)) * 8)) = h.i;
  }
  __syncthreads();

  int xk0 = (khi8) ^ ((r16 & 7) * 8);        // swizzled k-offset, ks=0
  int xk1 = (32 + khi8) ^ ((r16 & 7) * 8);   // ks=1
  int a0[4], a1[4];
#pragma unroll
  for (int m = 0; m < 4; ++m) {
    int row = m * 16 + r16;
    a0[m] = row * 640 + ((khi8) ^ ((row & 7) * 8));
    a1[m] = row * 640 + ((32 + khi8) ^ ((row & 7) * 8));
  }

  // ---- durations side-pass (wave 0 only; LDS panel + L2-hot WdB) ----
  if (wid == 0) {
    f32x4 dz = {0.f, 0.f, 0.f, 0.f};
    f32x4 dacc[4] = {dz, dz, dz, dz};
    const u16* Wp = WdB + (size_t)r16 * 640 + khi8;
#pragma unroll 2
    for (int ko = 0; ko < 640; ko += 32) {
      FragI wd;
      wd.i = *(const int4*)(Wp + ko);
      int ks = (ko & 32);
#pragma unroll
      for (int m = 0; m < 4; ++m) {
        FragI am;
        am.i = *(const int4*)(As + ((ks ? a1[m] : a0[m]) + (ko & ~63)));
        dacc[m] = __builtin_amdgcn_mfma_f32_16x16x32_bf16(am.b, wd.b, dacc[m], 0, 0, 0);
      }
    }
    if (r16 < 5) {
      float bd = b_dur[r16];
#pragma unroll
      for (int m = 0; m < 4; ++m) {
        int row = bt * 64 + m * 16 + g4 * 4;
#pragma unroll
        for (int i = 0; i < 4; ++i)
          out[LOGITS_N + (size_t)(row + i) * 5 + r16] = dacc[m][i] + bd;
      }
    }
  }

  // ---- main K-loop: B-frags direct from global (L2-hot), A-frags from LDS ----
  int nb = wid * 64;
  const u16* Bp[4];
#pragma unroll
  for (int fn = 0; fn < 4; ++fn)
    Bp[fn] = WoB + (size_t)(nb + fn * 16 + r16) * 640 + khi8;

  f32x4 z = {0.f, 0.f, 0.f, 0.f};
  f32x4 acc[4][4];
#pragma unroll
  for (int i = 0; i < 4; ++i)
#pragma unroll
    for (int j = 0; j < 4; ++j) acc[i][j] = z;

#pragma unroll 4
  for (int ko = 0; ko < 640; ko += 32) {
    FragI bq[4];
#pragma unroll
    for (int fn = 0; fn < 4; ++fn)
      bq[fn].i = *(const int4*)(Bp[fn] + ko);
    int ks = (ko & 32);
    int kb = (ko & ~63);
    FragI aq[4];
#pragma unroll
    for (int m = 0; m < 4; ++m)
      aq[m].i = *(const int4*)(As + ((ks ? a1[m] : a0[m]) + kb));
#pragma unroll
    for (int m = 0; m < 4; ++m)
#pragma unroll
      for (int fn = 0; fn < 4; ++fn)
        acc[m][fn] = __builtin_amdgcn_mfma_f32_16x16x32_bf16(aq[m].b, bq[fn].b, acc[m][fn], 0, 0, 0);
  }

  // ---- epilogue: bias + store ----
  size_t rowbase = (size_t)bt * 64;
#pragma unroll
  for (int fn = 0; fn < 4; ++fn) {
    int col = nb + fn * 16 + r16;
    float bo = b_out[col];
#pragma unroll
    for (int m = 0; m < 4; ++m) {
      size_t row = rowbase + m * 16 + g4 * 4;
#pragma unroll
      for (int i = 0; i < 4; ++i)
        out[(row + i) * 1024 + col] = acc[m][fn][i] + bo;
    }
  }
}

extern "C" void kernel_launch(void* const* d_in, const int* in_sizes, int n_in,
                              void* d_out, int out_size, void* d_ws, size_t ws_size,
                              hipStream_t stream) {
  const float* encoder   = (const float*)d_in[0];
  const float* predictor = (const float*)d_in[1];
  const float* W_enc = (const float*)d_in[2];
  const float* b_enc = (const float*)d_in[3];
  const float* W_pred = (const float*)d_in[4];
  const float* b_pred = (const float*)d_in[5];
  const float* W_out = (const float*)d_in[6];
  const float* b_out = (const float*)d_in[7];
  const float* W_dur = (const float*)d_in[8];
  const float* b_dur = (const float*)d_in[9];
  float* out = (float*)d_out;

  char* ws = (char*)d_ws;
  u16* WoB    = (u16*)(ws);                // 1024*640*2 = 1,310,720 B
  u16* WdB    = (u16*)(ws + 1310720);      // 16*640*2   =     20,480 B
  float* encP = (float*)(ws + 1331200);    // 1024*640*4 =  2,621,440 B
  float* predP= (float*)(ws + 3952640);    // 256*640*4  =    655,360 B

  conv_v4<<<640, 256, 0, stream>>>(W_out, WoB, 163840);
  conv_wdur<<<40, 256, 0, stream>>>(W_dur, WdB);
  proj_gemm<<<dim3(16, 10), 256, 0, stream>>>(encoder, W_enc, b_enc, encP, 1024, 640, 1024);
  proj_gemm<<<dim3(4, 10), 256, 0, stream>>>(predictor, W_pred, b_pred, predP, 256, 640, 640);
  bt_fused<<<1024, 1024, 0, stream>>>(encP, predP, WoB, WdB, b_out, b_dur, out);
}

// Round 8
// 179.081 us; speedup vs baseline: 1.6475x; 1.4160x over previous
//
#include <hip/hip_runtime.h>

typedef unsigned short u16;
typedef unsigned int u32;

typedef __bf16 bf16x8 __attribute__((ext_vector_type(8)));
typedef float f32x4 __attribute__((ext_vector_type(4)));

union FragI { int4 i; bf16x8 b; u16 u[8]; };

__device__ __forceinline__ u16 f2bf(float x) {
  u32 u = __float_as_uint(x);
  u32 r = (u + 0x7fffu + ((u >> 16) & 1u)) >> 16;
  return (u16)r;
}
__device__ __forceinline__ float tanh_fast(float x) {
  float e = __expf(2.0f * x);
  return 1.0f - __fdividef(2.0f, e + 1.0f);
}
__device__ __forceinline__ bf16x8 load_cvt8(const float* __restrict__ p) {
  float4 f0 = *(const float4*)p;
  float4 f1 = *(const float4*)(p + 4);
  union { bf16x8 b; u16 u[8]; } t;
  t.u[0] = f2bf(f0.x); t.u[1] = f2bf(f0.y); t.u[2] = f2bf(f0.z); t.u[3] = f2bf(f0.w);
  t.u[4] = f2bf(f1.x); t.u[5] = f2bf(f1.y); t.u[6] = f2bf(f1.z); t.u[7] = f2bf(f1.w);
  return t.b;
}

#define GLDS(gptr, lptr) \
  __builtin_amdgcn_global_load_lds((const __attribute__((address_space(1))) u32*)(gptr), \
                                   (__attribute__((address_space(3))) u32*)(lptr), 16, 0, 0)

// ---------------- f32 -> bf16 conversion (W_out) ----------------
__global__ __launch_bounds__(256) void conv_v4(const float* __restrict__ in,
                                               u16* __restrict__ out, int n4) {
  int i = blockIdx.x * 256 + threadIdx.x;
  if (i >= n4) return;
  float4 f = ((const float4*)in)[i];
  union { u16 u[4]; int2 v; } o;
  o.u[0] = f2bf(f.x); o.u[1] = f2bf(f.y); o.u[2] = f2bf(f.z); o.u[3] = f2bf(f.w);
  ((int2*)out)[i] = o.v;
}

// W_dur [5][640] f32 -> padded bf16 [16][640] (rows 5..15 zero)
__global__ __launch_bounds__(256) void conv_wdur(const float* __restrict__ in,
                                                 u16* __restrict__ out) {
  int i = blockIdx.x * 256 + threadIdx.x;
  if (i < 16 * 640) out[i] = (i < 5 * 640) ? f2bf(in[i]) : (u16)0;
}

// ---------------- projection GEMM (f32 out; verified R1-R7) ----------------
__global__ __launch_bounds__(256) void proj_gemm(const float* __restrict__ A,
                                                 const float* __restrict__ Bw,
                                                 const float* __restrict__ bias,
                                                 float* __restrict__ C,
                                                 int M, int N, int K) {
  int tid = threadIdx.x;
  int lane = tid & 63, wid = tid >> 6;
  int m0 = blockIdx.x * 64, n0 = blockIdx.y * 64;
  int kper = K >> 2;
  int kbase = wid * kper;
  int ksteps = kper >> 5;
  int r16 = lane & 15, khi = (lane >> 4) * 8;

  f32x4 z = {0.f, 0.f, 0.f, 0.f};
  f32x4 acc[4][4];
  for (int i = 0; i < 4; ++i)
    for (int j = 0; j < 4; ++j) acc[i][j] = z;

  for (int ks = 0; ks < ksteps; ++ks) {
    int k = kbase + ks * 32 + khi;
    bf16x8 af[4], bf[4];
#pragma unroll
    for (int fm = 0; fm < 4; ++fm)
      af[fm] = load_cvt8(A + (size_t)(m0 + fm * 16 + r16) * K + k);
#pragma unroll
    for (int fn = 0; fn < 4; ++fn)
      bf[fn] = load_cvt8(Bw + (size_t)(n0 + fn * 16 + r16) * K + k);
#pragma unroll
    for (int fm = 0; fm < 4; ++fm)
#pragma unroll
      for (int fn = 0; fn < 4; ++fn)
        acc[fm][fn] = __builtin_amdgcn_mfma_f32_16x16x32_bf16(af[fm], bf[fn], acc[fm][fn], 0, 0, 0);
  }

  __shared__ float red[4][64][64];
#pragma unroll
  for (int fm = 0; fm < 4; ++fm)
#pragma unroll
    for (int fn = 0; fn < 4; ++fn)
#pragma unroll
      for (int i = 0; i < 4; ++i)
        red[wid][fm * 16 + (lane >> 4) * 4 + i][fn * 16 + r16] = acc[fm][fn][i];
  __syncthreads();
  for (int idx = tid; idx < 4096; idx += 256) {
    int r = idx >> 6, c = idx & 63;
    float s = red[0][r][c] + red[1][r][c] + red[2][r][c] + red[3][r][c] + bias[n0 + c];
    C[(size_t)(m0 + r) * N + n0 + c] = s;
  }
}

// ---------------- joint = tanh(enc + pred) -> bf16 ----------------
__global__ __launch_bounds__(256) void joint_tanh(const float* __restrict__ enc,
                                                  const float* __restrict__ pred,
                                                  u16* __restrict__ J) {
  const int total = 65536 * 80;
  for (int c = blockIdx.x * 256 + threadIdx.x; c < total; c += gridDim.x * 256) {
    int m = c / 80;
    int j = c - m * 80;
    int bt = m >> 6;
    int uu = m & 63;
    int b = bt >> 8;
    const float* ep = enc + bt * 640 + j * 8;
    const float* pp = pred + (b * 64 + uu) * 640 + j * 8;
    float4 e0 = *(const float4*)ep;
    float4 e1 = *(const float4*)(ep + 4);
    float4 p0 = *(const float4*)pp;
    float4 p1 = *(const float4*)(pp + 4);
    union { u16 u[8]; int4 v; } o;
    o.u[0] = f2bf(tanh_fast(e0.x + p0.x));
    o.u[1] = f2bf(tanh_fast(e0.y + p0.y));
    o.u[2] = f2bf(tanh_fast(e0.z + p0.z));
    o.u[3] = f2bf(tanh_fast(e0.w + p0.w));
    o.u[4] = f2bf(tanh_fast(e1.x + p1.x));
    o.u[5] = f2bf(tanh_fast(e1.y + p1.y));
    o.u[6] = f2bf(tanh_fast(e1.z + p1.z));
    o.u[7] = f2bf(tanh_fast(e1.w + p1.w));
    *(int4*)(J + (size_t)c * 8) = o.v;
  }
}

// ---------------- main GEMM: m97 point — 128x128, 32KB single-buffer LDS,
// 2-barrier loop, T2 swizzle (conflict-free), 3 blocks/CU co-residency ----------------
// J [65536][640] bf16, Wo [1024][640] bf16, Wd [16][640] bf16 (rows>=5 zero)
// out: logits f32 [65536][1024] at 0, durations f32 [65536][5] at 67108864
#define LOGITS_N 67108864

// Stage one 128x64 bf16 tile (16 KB): 4 x GLDS(16B) per thread (256 thr).
// LDS phys (row, chunk) holds logical (row, chunk ^ (row&7))  [T2 swizzle, 8-u16 chunks]
__device__ __forceinline__ void stage128(const u16* __restrict__ g, u16* l,
                                         int wid, int lane) {
  int rl = wid * 8 + (lane >> 3);           // row within 32-row group
  int cl = ((lane & 7) ^ (lane >> 3)) * 8;  // pre-swizzled source column
  const u16* gp = g + (size_t)rl * 640 + cl;
  u16* lp = l + wid * 512;                  // wave-uniform base; HW adds lane*16B
#pragma unroll
  for (int j = 0; j < 4; ++j)
    GLDS(gp + (size_t)j * 32 * 640, lp + j * 2048);
}

__global__ __launch_bounds__(256, 3) void main_gemm(const u16* __restrict__ J,
                                                    const u16* __restrict__ Wo,
                                                    const u16* __restrict__ Wd,
                                                    const float* __restrict__ b_out,
                                                    const float* __restrict__ b_dur,
                                                    float* __restrict__ out) {
  __shared__ __align__(16) u16 As[8192];   // 16 KB (128 x 64)
  __shared__ __align__(16) u16 Bs[8192];   // 16 KB  -> 32 KB total
  int tid = threadIdx.x;
  int lane = tid & 63, wid = tid >> 6;
  int bid = blockIdx.x;
  // XCD-aware swizzle: 4096 % 8 == 0 bijective; bn fastest -> A-strip L2 reuse on-XCD
  int swz = (bid & 7) * 512 + (bid >> 3);
  int bn = swz & 7, bm = swz >> 3;
  int m0 = bm * 128, n0 = bn * 128;
  int wr = wid >> 1, wc = wid & 1;
  int r16 = lane & 15, khi = (lane >> 4) * 8;
  int xorv = (r16 & 7) << 3;
  bool do_dur = (bn == 0);

  f32x4 z = {0.f, 0.f, 0.f, 0.f};
  f32x4 acc[4][4];
#pragma unroll
  for (int i = 0; i < 4; ++i)
#pragma unroll
    for (int j = 0; j < 4; ++j) acc[i][j] = z;
  f32x4 dacc[4] = {z, z, z, z};

  const u16* Jb = J + (size_t)m0 * 640;
  const u16* Wb = Wo + (size_t)n0 * 640;

  for (int t = 0; t < 10; ++t) {
    stage128(Jb + t * 64, As, wid, lane);
    stage128(Wb + t * 64, Bs, wid, lane);
    __syncthreads();  // compiler drains vmcnt(0) before s_barrier -> GLDS landed
#pragma unroll
    for (int ks = 0; ks < 2; ++ks) {
      int cks = (ks * 32 + khi) ^ xorv;
      FragI af[4], bfr[4], wd;
#pragma unroll
      for (int fn = 0; fn < 4; ++fn)
        bfr[fn].i = *(const int4*)(Bs + (wc * 64 + fn * 16 + r16) * 64 + cks);
#pragma unroll
      for (int fm = 0; fm < 4; ++fm)
        af[fm].i = *(const int4*)(As + (wr * 64 + fm * 16 + r16) * 64 + cks);
      if (do_dur)
        wd.i = *(const int4*)(Wd + (size_t)r16 * 640 + t * 64 + ks * 32 + khi);
#pragma unroll
      for (int fm = 0; fm < 4; ++fm) {
#pragma unroll
        for (int fn = 0; fn < 4; ++fn)
          acc[fm][fn] = __builtin_amdgcn_mfma_f32_16x16x32_bf16(af[fm].b, bfr[fn].b, acc[fm][fn], 0, 0, 0);
        if (do_dur)
          dacc[fm] = __builtin_amdgcn_mfma_f32_16x16x32_bf16(af[fm].b, wd.b, dacc[fm], 0, 0, 0);
      }
    }
    __syncthreads();  // all waves done reading before next stage overwrites
  }

  // epilogue
  int rb = m0 + wr * 64 + (lane >> 4) * 4;
  int cb = n0 + wc * 64 + r16;
#pragma unroll
  for (int fn = 0; fn < 4; ++fn) {
    int col = cb + fn * 16;
    float bo = b_out[col];
#pragma unroll
    for (int fm = 0; fm < 4; ++fm) {
      int row = rb + fm * 16;
#pragma unroll
      for (int i = 0; i < 4; ++i)
        out[(size_t)(row + i) * 1024 + col] = acc[fm][fn][i] + bo;
    }
  }
  if (do_dur && r16 < 5) {
    float bd = b_dur[r16];
#pragma unroll
    for (int fm = 0; fm < 4; ++fm) {
      int row = rb + fm * 16;
#pragma unroll
      for (int i = 0; i < 4; ++i)
        out[LOGITS_N + (size_t)(row + i) * 5 + r16] = dacc[fm][i] + bd;
    }
  }
}

extern "C" void kernel_launch(void* const* d_in, const int* in_sizes, int n_in,
                              void* d_out, int out_size, void* d_ws, size_t ws_size,
                              hipStream_t stream) {
  const float* encoder   = (const float*)d_in[0];
  const float* predictor = (const float*)d_in[1];
  const float* W_enc = (const float*)d_in[2];
  const float* b_enc = (const float*)d_in[3];
  const float* W_pred = (const float*)d_in[4];
  const float* b_pred = (const float*)d_in[5];
  const float* W_out = (const float*)d_in[6];
  const float* b_out = (const float*)d_in[7];
  const float* W_dur = (const float*)d_in[8];
  const float* b_dur = (const float*)d_in[9];
  float* out = (float*)d_out;

  char* ws = (char*)d_ws;
  u16* Jbuf    = (u16*)(ws);                   // 65536*640*2 = 83,886,080 B
  u16* WoutB   = (u16*)(ws + 83886080);        // 1024*640*2  =  1,310,720 B
  u16* WdurB   = (u16*)(ws + 85196800);        // 16*640*2    =     20,480 B
  float* encP  = (float*)(ws + 85217280);      // 1024*640*4  =  2,621,440 B
  float* predP = (float*)(ws + 87838720);      // 256*640*4   =    655,360 B

  conv_v4<<<640, 256, 0, stream>>>(W_out, WoutB, 163840);
  conv_wdur<<<40, 256, 0, stream>>>(W_dur, WdurB);
  proj_gemm<<<dim3(16, 10), 256, 0, stream>>>(encoder, W_enc, b_enc, encP, 1024, 640, 1024);
  proj_gemm<<<dim3(4, 10), 256, 0, stream>>>(predictor, W_pred, b_pred, predP, 256, 640, 640);
  joint_tanh<<<2048, 256, 0, stream>>>(encP, predP, Jbuf);
  main_gemm<<<4096, 256, 0, stream>>>(Jbuf, WoutB, WdurB, b_out, b_dur, out);
}